// Round 4
// baseline (208.572 us; speedup 1.0000x reference)
//
#include <hip/hip_runtime.h>

// CubePadding: x [B,6,C,H,W] fp32 -> out [B,6,C,H+2P,W+2P] fp32. Pure gather/copy.
// R3: 4 output rows per thread -> 4 independent 16B loads + 4 stores per thread
//     (MLP x4, wave count /4, decode amortized). Grid flattened: 1536*33*33
//     slots = exactly 6534 x 256 threads, zero tail waste.
// Face order: 0=back(fb) 1=down(fd) 2=front(ff) 3=left(fl) 4=right(fr) 5=top(ft)

constexpr int P = 2, B = 4, C = 64, H = 128, W = 128;
constexpr int Ho = H + 2 * P, Wo = W + 2 * P;
constexpr int NV = Wo / 4;                    // 33 float4 groups per row
constexpr int PLANES = B * 6 * C;             // 1536
constexpr int RPT = 4;                        // rows per thread
constexpr int IO = Ho / RPT;                  // 33 row-blocks
constexpr int SLOTS_PER_PLANE = IO * NV;      // 1089
constexpr int TOTAL_SLOTS = PLANES * SLOTS_PER_PLANE;  // 1,672,704 = 6534*256

typedef float vfloat4 __attribute__((ext_vector_type(4)));
typedef vfloat4 float4u __attribute__((aligned(4)));   // 8B-aligned 16B load ok

// ---- halo source maps (verified R0/R1) ----
__device__ __forceinline__ void top_map(int f, int t, int w, int& sf, int& r, int& col) {
    switch (f) {
        case 0:  sf = 5; r = P - 1 - t; col = w;         break;
        case 1:  sf = 2; r = H - P + t; col = w;         break;
        case 2:  sf = 5; r = H - P + t; col = w;         break;
        case 3:  sf = 5; r = w;         col = t;         break;
        case 4:  sf = 5; r = w;         col = W - 1 - t; break;
        default: sf = 0; r = P - 1 - t; col = w;         break;
    }
}
__device__ __forceinline__ void bot_map(int f, int t, int w, int& sf, int& r, int& col) {
    switch (f) {
        case 0:  sf = 1; r = H - 1 - t; col = w;         break;
        case 1:  sf = 0; r = H - 1 - t; col = w;         break;
        case 2:  sf = 1; r = t;         col = w;         break;
        case 3:  sf = 1; r = w;         col = P - 1 - t; break;
        case 4:  sf = 1; r = w;         col = W - P + t; break;
        default: sf = 2; r = t;         col = w;         break;
    }
}
__device__ __forceinline__ void lft_map(int f, int h, int l, int& sf, int& r, int& col) {
    switch (f) {
        case 0:  sf = 4; r = h;         col = W - P + l; break;
        case 1:  sf = 3; r = H - 1 - l; col = h;         break;
        case 2:  sf = 3; r = h;         col = W - P + l; break;
        case 3:  sf = 0; r = h;         col = W - P + l; break;
        case 4:  sf = 2; r = h;         col = W - P + l; break;
        default: sf = 3; r = l;         col = h;         break;
    }
}
__device__ __forceinline__ void rgt_map(int f, int h, int rr, int& sf, int& r, int& col) {
    switch (f) {
        case 0:  sf = 3; r = h;          col = rr;        break;
        case 1:  sf = 4; r = H - P + rr; col = h;         break;
        case 2:  sf = 4; r = h;          col = rr;        break;
        case 3:  sf = 2; r = h;          col = rr;        break;
        case 4:  sf = 0; r = h;          col = rr;        break;
        default: sf = 4; r = P - 1 - rr; col = h;         break;
    }
}
__device__ __forceinline__ void gen_map(int f, int i, int j, int& sf, int& r, int& col) {
    bool in_h = (i >= P) && (i < H + P);
    bool in_w = (j >= P) && (j < W + P);
    if (in_h && in_w) {
        sf = f; r = i - P; col = j - P;
    } else if (!in_h) {
        int w = in_w ? (j - P) : (j < P ? 0 : W - 1);   // corners replicate strip edge
        if (i < P) top_map(f, i, w, sf, r, col);
        else       bot_map(f, i - H - P, w, sf, r, col);
    } else {
        if (j < P) lft_map(f, i - P, j,         sf, r, col);
        else       rgt_map(f, i - P, j - W - P, sf, r, col);
    }
}

__global__ __launch_bounds__(256) void cubepad_r4_kernel(const float* __restrict__ x,
                                                         float* __restrict__ out) {
    int slot  = blockIdx.x * 256 + threadIdx.x;
    int plane = slot / SLOTS_PER_PLANE;           // (b*6+f)*C + c
    int rem   = slot - plane * SLOTS_PER_PLANE;
    int io    = rem / NV;
    int v     = rem - io * NV;
    int i0    = io * RPT;                         // first of 4 output rows

    const float* __restrict__ xp = x + (size_t)plane * (H * W);
    float*       __restrict__ op = out + (size_t)plane * (Ho * Wo);

    bool fastall = (io >= 1) && (io < IO - 1) && (v >= 1) && (v < NV - 1);
    if (fastall) {
        // 4 independent loads first (MLP=4), then 4 stores
        const float* s = xp + (i0 - P) * W + (4 * v - P);
        float4u t0 = *(const float4u*)(s);
        float4u t1 = *(const float4u*)(s + W);
        float4u t2 = *(const float4u*)(s + 2 * W);
        float4u t3 = *(const float4u*)(s + 3 * W);
        float* o = op + i0 * Wo + 4 * v;
        *(vfloat4*)(o)          = t0;
        *(vfloat4*)(o + Wo)     = t1;
        *(vfloat4*)(o + 2 * Wo) = t2;
        *(vfloat4*)(o + 3 * Wo) = t3;
    } else {
        const int f  = (plane / C) % 6;
        const int bC = plane - f * C;             // b*6*C + c
        #pragma unroll
        for (int r4 = 0; r4 < RPT; ++r4) {
            int i = i0 + r4;
            float4 val;
            float* vp = (float*)&val;
            #pragma unroll
            for (int e = 0; e < 4; ++e) {
                int sf, r, col;
                gen_map(f, i, 4 * v + e, sf, r, col);
                vp[e] = x[((size_t)(bC + sf * C)) * (H * W) + (size_t)r * W + col];
            }
            *(float4*)(op + i * Wo + 4 * v) = val;
        }
    }
}

extern "C" void kernel_launch(void* const* d_in, const int* in_sizes, int n_in,
                              void* d_out, int out_size, void* d_ws, size_t ws_size,
                              hipStream_t stream) {
    const float* x = (const float*)d_in[0];
    float* out = (float*)d_out;
    cubepad_r4_kernel<<<TOTAL_SLOTS / 256, 256, 0, stream>>>(x, out);
}

// Round 5
// 200.946 us; speedup vs baseline: 1.0380x; 1.0380x over previous
//
#include <hip/hip_runtime.h>

// CubePadding: x [B,6,C,H,W] fp32 -> out [B,6,C,H+2P,W+2P] fp32. Pure gather/copy.
// R4: one thread handles the SAME (f,c,i,v) slot across all 4 batches.
//     Batch stride = 384 planes, so f/c/(i,v)/gen_map are invariant -> decode
//     once, then 4 independent loads + 4 stores at constant strides (MLP x4).
//     Per-instruction access pattern is byte-identical to R2 (dense 1KB chunks).
//     Slots per batch = 384*4356 = 1,672,704 = exactly 6534 x 256 (no tail).
// Face order: 0=back(fb) 1=down(fd) 2=front(ff) 3=left(fl) 4=right(fr) 5=top(ft)

constexpr int P = 2, B = 4, C = 64, H = 128, W = 128;
constexpr int Ho = H + 2 * P, Wo = W + 2 * P;
constexpr int NV = Wo / 4;                       // 33 float4 groups per row
constexpr int PPB = 6 * C;                       // 384 planes per batch
constexpr int SLOTS_PER_PLANE = Ho * NV;         // 4356
constexpr int SLOTS = PPB * SLOTS_PER_PLANE;     // 1,672,704 = 6534*256
constexpr size_t BSI = (size_t)PPB * H * W;      // batch stride, input floats
constexpr size_t BSO = (size_t)PPB * Ho * Wo;    // batch stride, output floats

typedef float vfloat4 __attribute__((ext_vector_type(4)));
typedef vfloat4 float4u __attribute__((aligned(4)));   // 8B-aligned 16B load ok

// ---- halo source maps (verified R0-R3) ----
__device__ __forceinline__ void top_map(int f, int t, int w, int& sf, int& r, int& col) {
    switch (f) {
        case 0:  sf = 5; r = P - 1 - t; col = w;         break;
        case 1:  sf = 2; r = H - P + t; col = w;         break;
        case 2:  sf = 5; r = H - P + t; col = w;         break;
        case 3:  sf = 5; r = w;         col = t;         break;
        case 4:  sf = 5; r = w;         col = W - 1 - t; break;
        default: sf = 0; r = P - 1 - t; col = w;         break;
    }
}
__device__ __forceinline__ void bot_map(int f, int t, int w, int& sf, int& r, int& col) {
    switch (f) {
        case 0:  sf = 1; r = H - 1 - t; col = w;         break;
        case 1:  sf = 0; r = H - 1 - t; col = w;         break;
        case 2:  sf = 1; r = t;         col = w;         break;
        case 3:  sf = 1; r = w;         col = P - 1 - t; break;
        case 4:  sf = 1; r = w;         col = W - P + t; break;
        default: sf = 2; r = t;         col = w;         break;
    }
}
__device__ __forceinline__ void lft_map(int f, int h, int l, int& sf, int& r, int& col) {
    switch (f) {
        case 0:  sf = 4; r = h;         col = W - P + l; break;
        case 1:  sf = 3; r = H - 1 - l; col = h;         break;
        case 2:  sf = 3; r = h;         col = W - P + l; break;
        case 3:  sf = 0; r = h;         col = W - P + l; break;
        case 4:  sf = 2; r = h;         col = W - P + l; break;
        default: sf = 3; r = l;         col = h;         break;
    }
}
__device__ __forceinline__ void rgt_map(int f, int h, int rr, int& sf, int& r, int& col) {
    switch (f) {
        case 0:  sf = 3; r = h;          col = rr;        break;
        case 1:  sf = 4; r = H - P + rr; col = h;         break;
        case 2:  sf = 4; r = h;          col = rr;        break;
        case 3:  sf = 2; r = h;          col = rr;        break;
        case 4:  sf = 0; r = h;          col = rr;        break;
        default: sf = 4; r = P - 1 - rr; col = h;         break;
    }
}
__device__ __forceinline__ void gen_map(int f, int i, int j, int& sf, int& r, int& col) {
    bool in_h = (i >= P) && (i < H + P);
    bool in_w = (j >= P) && (j < W + P);
    if (in_h && in_w) {
        sf = f; r = i - P; col = j - P;
    } else if (!in_h) {
        int w = in_w ? (j - P) : (j < P ? 0 : W - 1);   // corners replicate strip edge
        if (i < P) top_map(f, i, w, sf, r, col);
        else       bot_map(f, i - H - P, w, sf, r, col);
    } else {
        if (j < P) lft_map(f, i - P, j,         sf, r, col);
        else       rgt_map(f, i - P, j - W - P, sf, r, col);
    }
}

__global__ __launch_bounds__(256) void cubepad_b4_kernel(const float* __restrict__ x,
                                                         float* __restrict__ out) {
    int slot = blockIdx.x * 256 + threadIdx.x;       // slot within batch 0
    int pib  = slot / SLOTS_PER_PLANE;               // f*C + c   (plane in batch)
    int rem  = slot - pib * SLOTS_PER_PLANE;
    int i    = rem / NV;
    int v    = rem - i * NV;

    const float* __restrict__ xp = x   + (size_t)pib * (H * W);
    float*       __restrict__ op = out + (size_t)pib * (Ho * Wo);

    bool fast = (i >= P) && (i < H + P) && (v >= 1) && (v < NV - 1);
    if (fast) {
        const float* s = xp + (i - P) * W + (4 * v - P);
        float4u t0 = *(const float4u*)(s);
        float4u t1 = *(const float4u*)(s + BSI);
        float4u t2 = *(const float4u*)(s + 2 * BSI);
        float4u t3 = *(const float4u*)(s + 3 * BSI);
        float* o = op + i * Wo + 4 * v;
        *(vfloat4*)(o)           = t0;
        *(vfloat4*)(o + BSO)     = t1;
        *(vfloat4*)(o + 2 * BSO) = t2;
        *(vfloat4*)(o + 3 * BSO) = t3;
    } else {
        int f = pib / C;
        int c = pib - f * C;
        float4 val[4];
        #pragma unroll
        for (int e = 0; e < 4; ++e) {
            int sf, r, col;
            gen_map(f, i, 4 * v + e, sf, r, col);   // invariant across batches
            size_t so = ((size_t)(sf * C + c)) * (H * W) + (size_t)r * W + col;
            #pragma unroll
            for (int b = 0; b < 4; ++b)
                ((float*)&val[b])[e] = x[so + b * BSI];
        }
        float* o = op + i * Wo + 4 * v;
        #pragma unroll
        for (int b = 0; b < 4; ++b)
            *(float4*)(o + b * BSO) = val[b];
    }
}

extern "C" void kernel_launch(void* const* d_in, const int* in_sizes, int n_in,
                              void* d_out, int out_size, void* d_ws, size_t ws_size,
                              hipStream_t stream) {
    const float* x = (const float*)d_in[0];
    float* out = (float*)d_out;
    cubepad_b4_kernel<<<SLOTS / 256, 256, 0, stream>>>(x, out);
}